// Round 4
// baseline (101.438 us; speedup 1.0000x reference)
//
#include <hip/hip_runtime.h>
#include <math.h>

// CompressedAttention: B=4,S=4096,H=2,KVH=1,D=2,MD=5
// scores_ij = al_{h,i}*P_j + be_{h,i}*Q_j (rank-2); v colinear -> scalar out weight.
// R10: dual-pipe exp. Evidence from R7/R8/R9 (kernel ~12.5-13.5us invariant
// across LDS/occupancy configs): v_exp_f32 = ~16cyc/wave64 (trans stayed
// quarter-of-SIMD-16 rate on CDNA4) -> trans floor 13.6us with ALL exps on
// trans, VALU only ~35% busy. Fix: odd k-units compute exp2 via packed-VALU
// polynomial (round via 1.5*2^23 trick, int-domain n extraction so fast-math
// can't fold, degree-4 2^f Taylor err ~6e-5, v_ldexp_f32 scale -> no clamp
// needed), even k-units stay on v_exp_f32. Per-unit: trans 32->16, VALU
// 11->~20 -> balanced ~20cyc/unit -> main loop ~8.7us.
// Base = R8 best: BLOCK=512, RPT=4, grid 512 (2 blocks/CU, 4 waves/SIMD).

#define BQ 4
#define SQ 4096
#define MDQ 5
#define EPSQ 1e-6f
#define SCALEQ 16.0f
#define L2E 1.4426950408889634f
#define ISQ2 0.70710678118654752f
#define KRND 12582912.0f          // 1.5 * 2^23 round-to-int magic

typedef float v2f __attribute__((ext_vector_type(2)));

__device__ __forceinline__ float fast_exp2(float x) {
#if __has_builtin(__builtin_amdgcn_exp2f)
    return __builtin_amdgcn_exp2f(x);
#else
    return __expf(x * 0.6931471805599453f);
#endif
}

__device__ __forceinline__ float fast_ldexp(float x, int n) {
#if __has_builtin(__builtin_amdgcn_ldexpf)
    return __builtin_amdgcn_ldexpf(x, n);
#else
    return ldexpf(x, n);
#endif
}

#define BLOCK 512
#define WAVES 8             // waves per block
#define RPT 4               // rows per thread (per wave)
#define ROWSB (WAVES * RPT) // 32 rows per block
#define TILES (SQ / ROWSB)  // 128 tiles per batch -> grid 512 (2 blocks/CU)
#define KPT (SQ / BLOCK)    // 8 keys per thread in prep phase
#define JPT (SQ / 64)       // 64 inner iterations (keys per lane)

__global__ __launch_bounds__(BLOCK, 4)
void ca_fused(const float* __restrict__ x,
              const float* __restrict__ freqs,
              const float* __restrict__ qk_v,
              const float* __restrict__ v_v,
              const float* __restrict__ o_v,
              const float* __restrict__ vproj_u,
              const float* __restrict__ q_u,
              const float* __restrict__ k_u,
              const float* __restrict__ o_u,
              float* __restrict__ out)
{
    __shared__ float4 sKey[SQ];   // 64 KB: (P, Q, Cv, Cv) per key

    const int tid = threadIdx.x;
    const int sp  = tid & 63;        // key lane within wave
    const int w   = tid >> 6;        // wave index
    const int bx  = blockIdx.x;
    const int b   = bx / TILES;
    const int tile = bx % TILES;

    // ---- tiny shared params (broadcast / scalar loads) ----
    const float w0 = k_u[0], w1 = k_u[1];
    const float mk  = 0.5f * (w0 * w0 + w1 * w1);
    const float Mmu = SCALEQ * rsqrtf(mk);     // exact bound on |mu_j|

    const float qk0 = qk_v[0], qk1 = qk_v[1], qk2 = qk_v[2], qk3 = qk_v[3], qk4 = qk_v[4];
    const float vv0 = v_v[0],  vv1 = v_v[1],  vv2 = v_v[2],  vv3 = v_v[3],  vv4 = v_v[4];

    // ---- prep phase: 8 keys per thread into LDS ----
#pragma unroll
    for (int kk = 0; kk < KPT; ++kk) {
        const int j = tid + kk * BLOCK;
        const float* xr = x + (size_t)(b * SQ + j) * MDQ;
        const float x0 = xr[0], x1 = xr[1], x2 = xr[2], x3 = xr[3], x4 = xr[4];
        const float a  = x0*qk0 + x1*qk1 + x2*qk2 + x3*qk3 + x4*qk4;
        const float sv = x0*vv0 + x1*vv1 + x2*vv2 + x3*vv3 + x4*vv4;
        float sj, cj;
        __sincosf(freqs[j], &sj, &cj);
        const float mu = SCALEQ * a * rsqrtf(a * a * mk + EPSQ);   // rmsnorm(k) scalar
        sKey[j] = make_float4(mu * cj, mu * sj, sv, sv);           // Cv duplicated
    }

    // ---- per-row score coefficients, heads packed in v2f lanes ----
    const float u00 = q_u[0], u01 = q_u[1], u10 = q_u[2], u11 = q_u[3];
    const float m0 = 0.5f * (u00 * u00 + u01 * u01);
    const float m1 = 0.5f * (u10 * u10 + u11 * u11);
    const float A0 = u00 * w0 + u01 * w1, B0 = u01 * w0 - u00 * w1;
    const float A1 = u10 * w0 + u11 * w1, B1 = u11 * w0 - u10 * w1;

    const int i0 = tile * ROWSB + w * RPT;   // first row of this wave

    v2f al[RPT], be[RPT], Cc[RPT];
#pragma unroll
    for (int k = 0; k < RPT; ++k) {
        const int i = i0 + k;
        const float* xi = x + (size_t)(b * SQ + i) * MDQ;
        const float ai = xi[0]*qk0 + xi[1]*qk1 + xi[2]*qk2 + xi[3]*qk3 + xi[4]*qk4;
        float si, ci;
        __sincosf(freqs[i], &si, &ci);
        const float lam0 = SCALEQ * ai * rsqrtf(ai * ai * m0 + EPSQ);
        const float lam1 = SCALEQ * ai * rsqrtf(ai * ai * m1 + EPSQ);
        const float a0  = lam0 * (A0 * ci - B0 * si) * ISQ2;
        const float b0_ = lam0 * (A0 * si + B0 * ci) * ISQ2;
        const float a1  = lam1 * (A1 * ci - B1 * si) * ISQ2;
        const float b1_ = lam1 * (A1 * si + B1 * ci) * ISQ2;
        const float r0 = sqrtf(a0 * a0 + b0_ * b0_);
        const float r1 = sqrtf(a1 * a1 + b1_ * b1_);
        al[k] = (v2f){a0 * L2E, a1 * L2E};
        be[k] = (v2f){b0_ * L2E, b1_ * L2E};
        Cc[k] = (v2f){-r0 * Mmu * L2E, -r1 * Mmu * L2E};
    }

    __syncthreads();   // key table complete

    // ---- main loop: all keys from static LDS, no further barriers ----
    v2f l[RPT], n[RPT];
#pragma unroll
    for (int k = 0; k < RPT; ++k) { l[k] = (v2f){0.f, 0.f}; n[k] = (v2f){0.f, 0.f}; }

    // degree-4 Taylor of 2^f on [-0.5, 0.5] (rel err ~6e-5)
    const v2f pc0 = (v2f){1.0f, 1.0f};
    const v2f pc1 = (v2f){0.6931471806f, 0.6931471806f};
    const v2f pc2 = (v2f){0.2402265070f, 0.2402265070f};
    const v2f pc3 = (v2f){0.0555041087f, 0.0555041087f};
    const v2f pc4 = (v2f){0.0096181291f, 0.0096181291f};
    const v2f Kr  = (v2f){KRND, KRND};

    const float4* __restrict__ kb = &sKey[sp];
#pragma unroll 8
    for (int jj = 0; jj < JPT; ++jj) {
        const float4 v = kb[jj * 64];
        const v2f vx = (v2f){v.x, v.x};
        const v2f vy = (v2f){v.y, v.y};
        const v2f vz = (v2f){v.z, v.w};      // Cv duplicated by prep
#pragma unroll
        for (int k = 0; k < RPT; ++k) {
            const v2f s = al[k] * vx + (be[k] * vy + Cc[k]);   // 2x v_pk_fma
            v2f e;
            if (k & 1) {
                // packed-VALU polynomial exp2: both heads in v_pk ops
                const v2f t = s + Kr;                           // pk_add
                const int n0 = __float_as_int(t.x) - 0x4B400000;  // int-domain n
                const int n1 = __float_as_int(t.y) - 0x4B400000;  // (fast-math-proof)
                const v2f nf = (v2f){(float)n0, (float)n1};       // 2x v_cvt_f32_i32
                const v2f f = s - nf;                           // pk_add(neg)
                v2f p = pc4 * f + pc3;                          // 4x pk_fma
                p = p * f + pc2;
                p = p * f + pc1;
                p = p * f + pc0;
                e.x = fast_ldexp(p.x, n0);                      // v_ldexp_f32:
                e.y = fast_ldexp(p.y, n1);                      //  exact 2^n, no clamp
            } else {
                // trans pipe
                e.x = fast_exp2(s.x);
                e.y = fast_exp2(s.y);
            }
            l[k] += e;                        // v_pk_add
            n[k] += e * vz;                   // v_pk_fma
        }
    }

    // ---- full-wave butterfly reduction (64 key-lanes of this wave) ----
#pragma unroll
    for (int m = 1; m < 64; m <<= 1) {
#pragma unroll
        for (int k = 0; k < RPT; ++k) {
            l[k].x += __shfl_xor(l[k].x, m, 64);
            l[k].y += __shfl_xor(l[k].y, m, 64);
            n[k].x += __shfl_xor(n[k].x, m, 64);
            n[k].y += __shfl_xor(n[k].y, m, 64);
        }
    }

    // ---- epilogue: lanes 0..RPT-1 each write one row ----
    if (sp < RPT) {
        const int k = sp;
        const float L0 = fmaxf(l[k].x, 1e-30f);
        const float L1 = fmaxf(l[k].y, 1e-30f);
        const float W0 = n[k].x / L0, W1 = n[k].y / L1;

        const float p0 = vproj_u[0], p1 = vproj_u[1];
        const float d0 = p0 * o_v[0] + p1 * o_v[1];
        const float d1 = p0 * o_v[2] + p1 * o_v[3];
        const float so = W0 * d0 + W1 * d1;

        float* orow = out + (size_t)(b * SQ + i0 + k) * MDQ;
        orow[0] = so * o_u[0];
        orow[1] = so * o_u[1];
        orow[2] = so * o_u[2];
        orow[3] = so * o_u[3];
        orow[4] = so * o_u[4];
    }
}

extern "C" void kernel_launch(void* const* d_in, const int* in_sizes, int n_in,
                              void* d_out, int out_size, void* d_ws, size_t ws_size,
                              hipStream_t stream) {
    (void)in_sizes; (void)n_in; (void)out_size; (void)d_ws; (void)ws_size;
    const float* x       = (const float*)d_in[0];
    const float* freqs   = (const float*)d_in[1];
    const float* qk_v    = (const float*)d_in[2];
    const float* v_v     = (const float*)d_in[3];
    const float* o_v     = (const float*)d_in[4];
    const float* vproj_u = (const float*)d_in[5];
    const float* q_u     = (const float*)d_in[6];
    const float* k_u     = (const float*)d_in[7];
    const float* o_u     = (const float*)d_in[8];
    float* out = (float*)d_out;

    hipLaunchKernelGGL(ca_fused, dim3(BQ * TILES), dim3(BLOCK), 0, stream,
                       x, freqs, qk_v, v_v, o_v, vproj_u, q_u, k_u, o_u, out);
}

// Round 5
// 98.822 us; speedup vs baseline: 1.0265x; 1.0265x over previous
//
#include <hip/hip_runtime.h>
#include <math.h>

// CompressedAttention: B=4,S=4096,H=2,KVH=1,D=2,MD=5
// scores_ij = al_{h,i}*P_j + be_{h,i}*Q_j (rank-2); v colinear -> scalar out weight.
// R11: R8 base (BLOCK=512, RPT=4, grid 512 = 2 blocks/CU, 4 waves/SIMD,
// 64KB whole-table LDS) + lean 1:4 VALU exp offload.
// Evidence: R7/R8/R9 invariant ~12.5-13.5us = trans floor (v_exp_f32 ~16cy/
// wave-exp, 2048 wave-exps/SIMD). R10's 1:1 poly offload regressed 3x:
// scalarized + ldexpf libcall -> ~47 instr/pair on VALU. Fix here:
// only k==3 on poly (trans -> 3/4 = 10.2us) and ldexp replaced by integer
// exponent-add (sub/lshl/add, no libcall), clamp s>=-120 keeps bit-trick
// exact-safe (row max sits near 0; clamped tail <=2^-120 is invisible).
// Even fully-scalarized poly (~48cy/pair) -> VALU ~8.5us < 10.2us trans.

#define BQ 4
#define SQ 4096
#define MDQ 5
#define EPSQ 1e-6f
#define SCALEQ 16.0f
#define L2E 1.4426950408889634f
#define ISQ2 0.70710678118654752f
#define KRND 12582912.0f          // 1.5 * 2^23 round-to-int magic
#define KBIAS 0x4B400000          // bit pattern of KRND

typedef float v2f __attribute__((ext_vector_type(2)));

__device__ __forceinline__ float fast_exp2(float x) {
#if __has_builtin(__builtin_amdgcn_exp2f)
    return __builtin_amdgcn_exp2f(x);
#else
    return __expf(x * 0.6931471805599453f);
#endif
}

#define BLOCK 512
#define WAVES 8             // waves per block
#define RPT 4               // rows per thread (per wave)
#define ROWSB (WAVES * RPT) // 32 rows per block
#define TILES (SQ / ROWSB)  // 128 tiles per batch -> grid 512 (2 blocks/CU)
#define KPT (SQ / BLOCK)    // 8 keys per thread in prep phase
#define JPT (SQ / 64)       // 64 inner iterations (keys per lane)

__global__ __launch_bounds__(BLOCK, 4)
void ca_fused(const float* __restrict__ x,
              const float* __restrict__ freqs,
              const float* __restrict__ qk_v,
              const float* __restrict__ v_v,
              const float* __restrict__ o_v,
              const float* __restrict__ vproj_u,
              const float* __restrict__ q_u,
              const float* __restrict__ k_u,
              const float* __restrict__ o_u,
              float* __restrict__ out)
{
    __shared__ float4 sKey[SQ];   // 64 KB: (P, Q, Cv, Cv) per key

    const int tid = threadIdx.x;
    const int sp  = tid & 63;        // key lane within wave
    const int w   = tid >> 6;        // wave index
    const int bx  = blockIdx.x;
    const int b   = bx / TILES;
    const int tile = bx % TILES;

    // ---- tiny shared params (broadcast / scalar loads) ----
    const float w0 = k_u[0], w1 = k_u[1];
    const float mk  = 0.5f * (w0 * w0 + w1 * w1);
    const float Mmu = SCALEQ * rsqrtf(mk);     // exact bound on |mu_j|

    const float qk0 = qk_v[0], qk1 = qk_v[1], qk2 = qk_v[2], qk3 = qk_v[3], qk4 = qk_v[4];
    const float vv0 = v_v[0],  vv1 = v_v[1],  vv2 = v_v[2],  vv3 = v_v[3],  vv4 = v_v[4];

    // ---- prep phase: 8 keys per thread into LDS ----
#pragma unroll
    for (int kk = 0; kk < KPT; ++kk) {
        const int j = tid + kk * BLOCK;
        const float* xr = x + (size_t)(b * SQ + j) * MDQ;
        const float x0 = xr[0], x1 = xr[1], x2 = xr[2], x3 = xr[3], x4 = xr[4];
        const float a  = x0*qk0 + x1*qk1 + x2*qk2 + x3*qk3 + x4*qk4;
        const float sv = x0*vv0 + x1*vv1 + x2*vv2 + x3*vv3 + x4*vv4;
        float sj, cj;
        __sincosf(freqs[j], &sj, &cj);
        const float mu = SCALEQ * a * rsqrtf(a * a * mk + EPSQ);   // rmsnorm(k) scalar
        sKey[j] = make_float4(mu * cj, mu * sj, sv, sv);           // Cv duplicated
    }

    // ---- per-row score coefficients, heads packed in v2f lanes ----
    const float u00 = q_u[0], u01 = q_u[1], u10 = q_u[2], u11 = q_u[3];
    const float m0 = 0.5f * (u00 * u00 + u01 * u01);
    const float m1 = 0.5f * (u10 * u10 + u11 * u11);
    const float A0 = u00 * w0 + u01 * w1, B0 = u01 * w0 - u00 * w1;
    const float A1 = u10 * w0 + u11 * w1, B1 = u11 * w0 - u10 * w1;

    const int i0 = tile * ROWSB + w * RPT;   // first row of this wave

    v2f al[RPT], be[RPT], Cc[RPT];
#pragma unroll
    for (int k = 0; k < RPT; ++k) {
        const int i = i0 + k;
        const float* xi = x + (size_t)(b * SQ + i) * MDQ;
        const float ai = xi[0]*qk0 + xi[1]*qk1 + xi[2]*qk2 + xi[3]*qk3 + xi[4]*qk4;
        float si, ci;
        __sincosf(freqs[i], &si, &ci);
        const float lam0 = SCALEQ * ai * rsqrtf(ai * ai * m0 + EPSQ);
        const float lam1 = SCALEQ * ai * rsqrtf(ai * ai * m1 + EPSQ);
        const float a0  = lam0 * (A0 * ci - B0 * si) * ISQ2;
        const float b0_ = lam0 * (A0 * si + B0 * ci) * ISQ2;
        const float a1  = lam1 * (A1 * ci - B1 * si) * ISQ2;
        const float b1_ = lam1 * (A1 * si + B1 * ci) * ISQ2;
        const float r0 = sqrtf(a0 * a0 + b0_ * b0_);
        const float r1 = sqrtf(a1 * a1 + b1_ * b1_);
        al[k] = (v2f){a0 * L2E, a1 * L2E};
        be[k] = (v2f){b0_ * L2E, b1_ * L2E};
        Cc[k] = (v2f){-r0 * Mmu * L2E, -r1 * Mmu * L2E};
    }

    __syncthreads();   // key table complete

    // ---- main loop: all keys from static LDS, no further barriers ----
    v2f l[RPT], n[RPT];
#pragma unroll
    for (int k = 0; k < RPT; ++k) { l[k] = (v2f){0.f, 0.f}; n[k] = (v2f){0.f, 0.f}; }

    // degree-4 Taylor of 2^f on [-0.5, 0.5] (rel err ~6e-5)
    const v2f pc0 = (v2f){1.0f, 1.0f};
    const v2f pc1 = (v2f){0.6931471806f, 0.6931471806f};
    const v2f pc2 = (v2f){0.2402265070f, 0.2402265070f};
    const v2f pc3 = (v2f){0.0555041087f, 0.0555041087f};
    const v2f pc4 = (v2f){0.0096181291f, 0.0096181291f};

    const float4* __restrict__ kb = &sKey[sp];
#pragma unroll 8
    for (int jj = 0; jj < JPT; ++jj) {
        const float4 v = kb[jj * 64];
        const v2f vx = (v2f){v.x, v.x};
        const v2f vy = (v2f){v.y, v.y};
        const v2f vz = (v2f){v.z, v.w};      // Cv duplicated by prep
#pragma unroll
        for (int k = 0; k < RPT; ++k) {
            const v2f s = al[k] * vx + (be[k] * vy + Cc[k]);   // 2x v_pk_fma
            v2f e;
            if (k == 3) {
                // lean VALU exp2: round-magic + deg-4 poly + integer
                // exponent-add (no ldexp libcall). s clamped to [-120, 0]
                // so the bit-scale never underflows (tail <= 2^-120).
                v2f sc;
                sc.x = fmaxf(s.x, -120.0f);
                sc.y = fmaxf(s.y, -120.0f);
                const float t0 = sc.x + KRND;
                const float t1 = sc.y + KRND;
                const int nn0 = KBIAS - __float_as_int(t0);   // = -round(s)
                const int nn1 = KBIAS - __float_as_int(t1);
                v2f f;
                f.x = sc.x + (float)nn0;                      // s - n in [-.5,.5]
                f.y = sc.y + (float)nn1;
                v2f p = pc4 * f + pc3;
                p = p * f + pc2;
                p = p * f + pc1;
                p = p * f + pc0;
                e.x = __int_as_float(__float_as_int(p.x) - (nn0 << 23));
                e.y = __int_as_float(__float_as_int(p.y) - (nn1 << 23));
            } else {
                // trans pipe
                e.x = fast_exp2(s.x);
                e.y = fast_exp2(s.y);
            }
            l[k] += e;                        // v_pk_add
            n[k] += e * vz;                   // v_pk_fma
        }
    }

    // ---- full-wave butterfly reduction (64 key-lanes of this wave) ----
#pragma unroll
    for (int m = 1; m < 64; m <<= 1) {
#pragma unroll
        for (int k = 0; k < RPT; ++k) {
            l[k].x += __shfl_xor(l[k].x, m, 64);
            l[k].y += __shfl_xor(l[k].y, m, 64);
            n[k].x += __shfl_xor(n[k].x, m, 64);
            n[k].y += __shfl_xor(n[k].y, m, 64);
        }
    }

    // ---- epilogue: lanes 0..RPT-1 each write one row ----
    if (sp < RPT) {
        const int k = sp;
        const float L0 = fmaxf(l[k].x, 1e-30f);
        const float L1 = fmaxf(l[k].y, 1e-30f);
        const float W0 = n[k].x / L0, W1 = n[k].y / L1;

        const float p0 = vproj_u[0], p1 = vproj_u[1];
        const float d0 = p0 * o_v[0] + p1 * o_v[1];
        const float d1 = p0 * o_v[2] + p1 * o_v[3];
        const float so = W0 * d0 + W1 * d1;

        float* orow = out + (size_t)(b * SQ + i0 + k) * MDQ;
        orow[0] = so * o_u[0];
        orow[1] = so * o_u[1];
        orow[2] = so * o_u[2];
        orow[3] = so * o_u[3];
        orow[4] = so * o_u[4];
    }
}

extern "C" void kernel_launch(void* const* d_in, const int* in_sizes, int n_in,
                              void* d_out, int out_size, void* d_ws, size_t ws_size,
                              hipStream_t stream) {
    (void)in_sizes; (void)n_in; (void)out_size; (void)d_ws; (void)ws_size;
    const float* x       = (const float*)d_in[0];
    const float* freqs   = (const float*)d_in[1];
    const float* qk_v    = (const float*)d_in[2];
    const float* v_v     = (const float*)d_in[3];
    const float* o_v     = (const float*)d_in[4];
    const float* vproj_u = (const float*)d_in[5];
    const float* q_u     = (const float*)d_in[6];
    const float* k_u     = (const float*)d_in[7];
    const float* o_u     = (const float*)d_in[8];
    float* out = (float*)d_out;

    hipLaunchKernelGGL(ca_fused, dim3(BQ * TILES), dim3(BLOCK), 0, stream,
                       x, freqs, qk_v, v_v, o_v, vproj_u, q_u, k_u, o_u, out);
}

// Round 6
// 93.171 us; speedup vs baseline: 1.0887x; 1.0607x over previous
//
#include <hip/hip_runtime.h>
#include <math.h>

// CompressedAttention: B=4,S=4096,H=2,KVH=1,D=2,MD=5
// scores_ij = al_{h,i}*P_j + be_{h,i}*Q_j (rank-2); v colinear -> scalar out weight.
// R12 = exact revert to R8 (best measured: dur 92.58us).
// Evidence summary: kernel is trans-pipe bound at ~12.6us (134M exps =
// 2048 wave-exps/SIMD x 16cyc v_exp_f32 = 13.6us model; R7/R8/R9 config-
// invariant). VALU exp-offload refuted twice (R10: scalarization+libcall,
// 3x regression; R11: scalarization+dep-chain stalls, +5us at 1:4 ratio) --
// hipcc will not emit packed VOP3P for the poly, and without packing the
// offload has no margin. Measurement window is ~86% harness poison fills
// (2 x 256MiB @ ~40us, themselves HBM-bound at 84%). This config:
// BLOCK=512, RPT=4, grid 512 = 2 blocks/CU (2x64KB LDS), 4 waves/SIMD.

#define BQ 4
#define SQ 4096
#define MDQ 5
#define EPSQ 1e-6f
#define SCALEQ 16.0f
#define L2E 1.4426950408889634f
#define ISQ2 0.70710678118654752f

typedef float v2f __attribute__((ext_vector_type(2)));

__device__ __forceinline__ float fast_exp2(float x) {
#if __has_builtin(__builtin_amdgcn_exp2f)
    return __builtin_amdgcn_exp2f(x);
#else
    return __expf(x * 0.6931471805599453f);
#endif
}

#define BLOCK 512
#define WAVES 8             // waves per block
#define RPT 4               // rows per thread (per wave)
#define ROWSB (WAVES * RPT) // 32 rows per block
#define TILES (SQ / ROWSB)  // 128 tiles per batch -> grid 512 (2 blocks/CU)
#define KPT (SQ / BLOCK)    // 8 keys per thread in prep phase
#define JPT (SQ / 64)       // 64 inner iterations (keys per lane)

__global__ __launch_bounds__(BLOCK, 4)
void ca_fused(const float* __restrict__ x,
              const float* __restrict__ freqs,
              const float* __restrict__ qk_v,
              const float* __restrict__ v_v,
              const float* __restrict__ o_v,
              const float* __restrict__ vproj_u,
              const float* __restrict__ q_u,
              const float* __restrict__ k_u,
              const float* __restrict__ o_u,
              float* __restrict__ out)
{
    __shared__ float4 sKey[SQ];   // 64 KB: (P, Q, Cv, Cv) per key

    const int tid = threadIdx.x;
    const int sp  = tid & 63;        // key lane within wave
    const int w   = tid >> 6;        // wave index
    const int bx  = blockIdx.x;
    const int b   = bx / TILES;
    const int tile = bx % TILES;

    // ---- tiny shared params (broadcast / scalar loads) ----
    const float w0 = k_u[0], w1 = k_u[1];
    const float mk  = 0.5f * (w0 * w0 + w1 * w1);
    const float Mmu = SCALEQ * rsqrtf(mk);     // exact bound on |mu_j|

    const float qk0 = qk_v[0], qk1 = qk_v[1], qk2 = qk_v[2], qk3 = qk_v[3], qk4 = qk_v[4];
    const float vv0 = v_v[0],  vv1 = v_v[1],  vv2 = v_v[2],  vv3 = v_v[3],  vv4 = v_v[4];

    // ---- prep phase: 8 keys per thread into LDS ----
#pragma unroll
    for (int kk = 0; kk < KPT; ++kk) {
        const int j = tid + kk * BLOCK;
        const float* xr = x + (size_t)(b * SQ + j) * MDQ;
        const float x0 = xr[0], x1 = xr[1], x2 = xr[2], x3 = xr[3], x4 = xr[4];
        const float a  = x0*qk0 + x1*qk1 + x2*qk2 + x3*qk3 + x4*qk4;
        const float sv = x0*vv0 + x1*vv1 + x2*vv2 + x3*vv3 + x4*vv4;
        float sj, cj;
        __sincosf(freqs[j], &sj, &cj);
        const float mu = SCALEQ * a * rsqrtf(a * a * mk + EPSQ);   // rmsnorm(k) scalar
        sKey[j] = make_float4(mu * cj, mu * sj, sv, sv);           // Cv duplicated
    }

    // ---- per-row score coefficients, heads packed in v2f lanes ----
    const float u00 = q_u[0], u01 = q_u[1], u10 = q_u[2], u11 = q_u[3];
    const float m0 = 0.5f * (u00 * u00 + u01 * u01);
    const float m1 = 0.5f * (u10 * u10 + u11 * u11);
    const float A0 = u00 * w0 + u01 * w1, B0 = u01 * w0 - u00 * w1;
    const float A1 = u10 * w0 + u11 * w1, B1 = u11 * w0 - u10 * w1;

    const int i0 = tile * ROWSB + w * RPT;   // first row of this wave

    v2f al[RPT], be[RPT], Cc[RPT];
#pragma unroll
    for (int k = 0; k < RPT; ++k) {
        const int i = i0 + k;
        const float* xi = x + (size_t)(b * SQ + i) * MDQ;
        const float ai = xi[0]*qk0 + xi[1]*qk1 + xi[2]*qk2 + xi[3]*qk3 + xi[4]*qk4;
        float si, ci;
        __sincosf(freqs[i], &si, &ci);
        const float lam0 = SCALEQ * ai * rsqrtf(ai * ai * m0 + EPSQ);
        const float lam1 = SCALEQ * ai * rsqrtf(ai * ai * m1 + EPSQ);
        const float a0  = lam0 * (A0 * ci - B0 * si) * ISQ2;
        const float b0_ = lam0 * (A0 * si + B0 * ci) * ISQ2;
        const float a1  = lam1 * (A1 * ci - B1 * si) * ISQ2;
        const float b1_ = lam1 * (A1 * si + B1 * ci) * ISQ2;
        const float r0 = sqrtf(a0 * a0 + b0_ * b0_);
        const float r1 = sqrtf(a1 * a1 + b1_ * b1_);
        al[k] = (v2f){a0 * L2E, a1 * L2E};
        be[k] = (v2f){b0_ * L2E, b1_ * L2E};
        Cc[k] = (v2f){-r0 * Mmu * L2E, -r1 * Mmu * L2E};
    }

    __syncthreads();   // key table complete

    // ---- main loop: all keys from static LDS, no further barriers ----
    v2f l[RPT], n[RPT];
#pragma unroll
    for (int k = 0; k < RPT; ++k) { l[k] = (v2f){0.f, 0.f}; n[k] = (v2f){0.f, 0.f}; }

    const float4* __restrict__ kb = &sKey[sp];
#pragma unroll 8
    for (int jj = 0; jj < JPT; ++jj) {
        const float4 v = kb[jj * 64];
        const v2f vx = (v2f){v.x, v.x};
        const v2f vy = (v2f){v.y, v.y};
        const v2f vz = (v2f){v.z, v.w};      // Cv duplicated by prep
#pragma unroll
        for (int k = 0; k < RPT; ++k) {
            const v2f s = al[k] * vx + (be[k] * vy + Cc[k]);   // 2x v_pk_fma
            v2f e;
            e.x = fast_exp2(s.x);
            e.y = fast_exp2(s.y);
            l[k] += e;                        // v_pk_add
            n[k] += e * vz;                   // v_pk_fma
        }
    }

    // ---- full-wave butterfly reduction (64 key-lanes of this wave) ----
#pragma unroll
    for (int m = 1; m < 64; m <<= 1) {
#pragma unroll
        for (int k = 0; k < RPT; ++k) {
            l[k].x += __shfl_xor(l[k].x, m, 64);
            l[k].y += __shfl_xor(l[k].y, m, 64);
            n[k].x += __shfl_xor(n[k].x, m, 64);
            n[k].y += __shfl_xor(n[k].y, m, 64);
        }
    }

    // ---- epilogue: lanes 0..RPT-1 each write one row ----
    if (sp < RPT) {
        const int k = sp;
        const float L0 = fmaxf(l[k].x, 1e-30f);
        const float L1 = fmaxf(l[k].y, 1e-30f);
        const float W0 = n[k].x / L0, W1 = n[k].y / L1;

        const float p0 = vproj_u[0], p1 = vproj_u[1];
        const float d0 = p0 * o_v[0] + p1 * o_v[1];
        const float d1 = p0 * o_v[2] + p1 * o_v[3];
        const float so = W0 * d0 + W1 * d1;

        float* orow = out + (size_t)(b * SQ + i0 + k) * MDQ;
        orow[0] = so * o_u[0];
        orow[1] = so * o_u[1];
        orow[2] = so * o_u[2];
        orow[3] = so * o_u[3];
        orow[4] = so * o_u[4];
    }
}

extern "C" void kernel_launch(void* const* d_in, const int* in_sizes, int n_in,
                              void* d_out, int out_size, void* d_ws, size_t ws_size,
                              hipStream_t stream) {
    (void)in_sizes; (void)n_in; (void)out_size; (void)d_ws; (void)ws_size;
    const float* x       = (const float*)d_in[0];
    const float* freqs   = (const float*)d_in[1];
    const float* qk_v    = (const float*)d_in[2];
    const float* v_v     = (const float*)d_in[3];
    const float* o_v     = (const float*)d_in[4];
    const float* vproj_u = (const float*)d_in[5];
    const float* q_u     = (const float*)d_in[6];
    const float* k_u     = (const float*)d_in[7];
    const float* o_u     = (const float*)d_in[8];
    float* out = (float*)d_out;

    hipLaunchKernelGGL(ca_fused, dim3(BQ * TILES), dim3(BLOCK), 0, stream,
                       x, freqs, qk_v, v_v, o_v, vproj_u, q_u, k_u, o_u, out);
}